// Round 4
// baseline (710.623 us; speedup 1.0000x reference)
//
#include <hip/hip_runtime.h>

#define N_NODES 100000
#define N_EDGES 1600000
#define NGRAPH  64
#define DIN     128
#define HID     256
#define GA      6

// bucketed CSR build
#define NBUCK  98        // ceil(100000 / 1024)
#define BSHIFT 10        // 1024 nodes per bucket
#define BCAP   20480     // per-bucket capacity (mean 16384, +32 sigma)

typedef __attribute__((ext_vector_type(8))) short bf16x8;
typedef __attribute__((ext_vector_type(4))) float f32x4;

__device__ __forceinline__ unsigned short f2bf(float f) {
  unsigned int u = __float_as_uint(f);
  u += 0x7fffu + ((u >> 16) & 1u);
  return (unsigned short)(u >> 16);
}
__device__ __forceinline__ float bf_lo(unsigned int u) { return __uint_as_float(u << 16); }
__device__ __forceinline__ float bf_hi(unsigned int u) { return __uint_as_float(u & 0xffff0000u); }
__device__ __forceinline__ unsigned int packbf(float lo, float hi) {
  return (unsigned int)f2bf(lo) | ((unsigned int)f2bf(hi) << 16);
}

__device__ __forceinline__ void gload16(const void* g, void* l) {
  __builtin_amdgcn_global_load_lds(
      (const __attribute__((address_space(1))) unsigned int*)g,
      (__attribute__((address_space(3))) unsigned int*)l, 16, 0, 0);
}

// ---------------- prep: f32 -> bf16 conversions ----------------

__global__ __launch_bounds__(256) void cvt_x_kernel(const float* __restrict__ in,
                                                    unsigned short* __restrict__ out) {
  size_t idx = ((size_t)blockIdx.x * 256 + threadIdx.x) * 4;  // 12.8M total, exact
  float4 v = *(const float4*)&in[idx];
  ushort4 o;
  o.x = f2bf(v.x); o.y = f2bf(v.y); o.z = f2bf(v.z); o.w = f2bf(v.w);
  *(ushort4*)&out[idx] = o;
}

// all four weight transposes in one launch: out[n*K+k] = bf16(in[k*256+n])
__global__ __launch_bounds__(256) void cvt_w_all(const float* __restrict__ w1a,
                                                 const float* __restrict__ w1b,
                                                 const float* __restrict__ w2a,
                                                 const float* __restrict__ w2b,
                                                 unsigned short* __restrict__ o1a,
                                                 unsigned short* __restrict__ o1b,
                                                 unsigned short* __restrict__ o2a,
                                                 unsigned short* __restrict__ o2b) {
  int bid = blockIdx.x, tid = threadIdx.x;
  const float* in; unsigned short* out; int shift, idx;
  if (bid < 128)      { in = w1a; out = o1a; shift = 7; idx = bid * 256 + tid; }
  else if (bid < 384) { in = w1b; out = o1b; shift = 8; idx = (bid - 128) * 256 + tid; }
  else if (bid < 640) { in = w2a; out = o2a; shift = 8; idx = (bid - 384) * 256 + tid; }
  else                { in = w2b; out = o2b; shift = 8; idx = (bid - 640) * 256 + tid; }
  int K = 1 << shift;
  int n = idx >> shift;
  int k = idx & (K - 1);
  out[idx] = f2bf(in[(size_t)k * HID + n]);
}

// ---------------- pass 1: bin edges by dst>>10 with block-local sort ----------------

__global__ __launch_bounds__(256) void bin_kernel(const int* __restrict__ esrc,
                                                  const int* __restrict__ edst,
                                                  int* __restrict__ cursor,
                                                  unsigned int* __restrict__ tmp) {
  __shared__ unsigned int pk[4096];
  __shared__ int hist[NBUCK], lbase[NBUCK + 1], gbase[NBUCK], lcur[NBUCK];
  const int tid = threadIdx.x;
  const int lane = tid & 63;
  const int ebase = blockIdx.x * 4096;
  const int n = min(4096, N_EDGES - ebase);
  if (tid < NBUCK) hist[tid] = 0;
  __syncthreads();
  unsigned int pkv[16]; int bk[16];
#pragma unroll
  for (int i = 0; i < 16; i++) {
    int e = ebase + i * 256 + tid;
    bk[i] = -1;
    if (e < N_EDGES) {
      int s = esrc[e], d = edst[e];
      bk[i] = d >> BSHIFT;
      pkv[i] = (unsigned int)s | ((unsigned int)(d & ((1 << BSHIFT) - 1)) << 17);
      atomicAdd(&hist[bk[i]], 1);
    }
  }
  __syncthreads();
  if (tid < 64) {
    int i0 = 2 * tid, i1 = i0 + 1;
    int a0 = (i0 < NBUCK) ? hist[i0] : 0;
    int a1 = (i1 < NBUCK) ? hist[i1] : 0;
    int p = a0 + a1, sc = p;
#pragma unroll
    for (int off = 1; off < 64; off <<= 1) {
      int t = __shfl_up(sc, off);
      if (lane >= off) sc += t;
    }
    int excl = sc - p;
    if (i0 < NBUCK) lbase[i0] = excl;
    if (i1 < NBUCK) lbase[i1] = excl + a0;
    if (tid == 63) lbase[NBUCK] = sc;
  }
  __syncthreads();
  if (tid < NBUCK) {
    int c = hist[tid];
    gbase[tid] = c ? atomicAdd(&cursor[tid], c) : 0;
    lcur[tid] = lbase[tid];
  }
  __syncthreads();
#pragma unroll
  for (int i = 0; i < 16; i++) {
    if (bk[i] >= 0) {
      int pos = atomicAdd(&lcur[bk[i]], 1);
      pk[pos] = pkv[i];
    }
  }
  __syncthreads();
#pragma unroll
  for (int i = 0; i < 16; i++) {
    int idx = i * 256 + tid;
    if (idx < n) {
      int lo = 0, hi = NBUCK;
      while (hi - lo > 1) {
        int mid = (lo + hi) >> 1;
        if (lbase[mid] <= idx) lo = mid; else hi = mid;
      }
      tmp[(size_t)lo * BCAP + gbase[lo] + (idx - lbase[lo])] = pk[idx];
    }
  }
}

// ---------------- pass 2: per-bucket counting sort -> csr + ssrc ----------------

__global__ __launch_bounds__(512) void sort_kernel(const unsigned int* __restrict__ tmp,
                                                   const int* __restrict__ cnt,
                                                   int* __restrict__ csr,
                                                   int* __restrict__ ssrc) {
  __shared__ int nhist[1024], ncur[1024];
  __shared__ int bb[NBUCK];
  __shared__ int wsum[8];
  const int b = blockIdx.x;
  const int tid = threadIdx.x;
  const int lane = tid & 63, wid = tid >> 6;
  if (tid < 64) {
    int i0 = 2 * tid, i1 = i0 + 1;
    int a0 = (i0 < NBUCK) ? cnt[i0] : 0;
    int a1 = (i1 < NBUCK) ? cnt[i1] : 0;
    int p = a0 + a1, sc = p;
#pragma unroll
    for (int off = 1; off < 64; off <<= 1) {
      int t = __shfl_up(sc, off);
      if (lane >= off) sc += t;
    }
    int excl = sc - p;
    if (i0 < NBUCK) bb[i0] = excl;
    if (i1 < NBUCK) bb[i1] = excl + a0;
  }
  nhist[tid] = 0; nhist[tid + 512] = 0;
  __syncthreads();
  const int myCnt = cnt[b];
  const int ebase = bb[b];
  const unsigned int* srcp = tmp + (size_t)b * BCAP;
  for (int i = tid; i < myCnt; i += 512)
    atomicAdd(&nhist[srcp[i] >> 17], 1);
  __syncthreads();
  int i0 = 2 * tid;
  int a0 = nhist[i0], a1 = nhist[i0 + 1];
  int p = a0 + a1, sc = p;
#pragma unroll
  for (int off = 1; off < 64; off <<= 1) {
    int t = __shfl_up(sc, off);
    if (lane >= off) sc += t;
  }
  if (lane == 63) wsum[wid] = sc;
  __syncthreads();
  if (tid < 8) {
    int ws = wsum[tid];
#pragma unroll
    for (int off = 1; off < 8; off <<= 1) {
      int t = __shfl_up(ws, off);
      if (tid >= off) ws += t;
    }
    wsum[tid] = ws;
  }
  __syncthreads();
  int excl = ((wid > 0) ? wsum[wid - 1] : 0) + sc - p;
  ncur[i0] = excl;
  ncur[i0 + 1] = excl + a0;
  int node0 = (b << BSHIFT) + i0;
  if (node0 < N_NODES) csr[node0] = ebase + excl;
  if (node0 + 1 < N_NODES) csr[node0 + 1] = ebase + excl + a0;
  if (b == 0 && tid == 0) csr[N_NODES] = N_EDGES;
  __syncthreads();
  for (int i = tid; i < myCnt; i += 512) {
    unsigned int pe = srcp[i];
    int pos = atomicAdd(&ncur[pe >> 17], 1);
    ssrc[ebase + pos] = (int)(pe & 0x1FFFF);
  }
}

// ---------------- fused conv: agg + Linear(K1->256) + ReLU + Linear(256->256) ----------------
// X [N][K1] bf16; W1t [256][K1] bf16; W2t [256][256] bf16; C [N][256] bf16.
// Block: 256 thr (4 waves, 1x4), tile 64 rows x 256 cols, BK=32.
// A-tile and h1 live entirely in LDS in the [ko][row][8] fragment layout.
template<int K1, bool RELU2>
__global__ __launch_bounds__(256, 3)
void conv_fused(const unsigned short* __restrict__ X,
                const int* __restrict__ csr,
                const int* __restrict__ ssrc,
                const unsigned short* __restrict__ W1t,
                const float* __restrict__ b1,
                const unsigned short* __restrict__ W2t,
                const float* __restrict__ b2,
                unsigned short* __restrict__ C) {
  constexpr int ASL = K1 * 64;     // A-tile elems: [K1/8][64][8]
  constexpr int HSL = 256 * 64;    // h1 elems: [32][64][8]
  __shared__ unsigned short AH[(K1 == 256) ? HSL : (ASL + HSL)];
  __shared__ unsigned short Wsl[4 * 256 * 8];   // 16 KB, streamed per BK=32
  unsigned short* AslF = AH;
  unsigned short* Hsl = (K1 == 256) ? AH : (AH + ASL);

  const int tid = threadIdx.x;
  const int lane = tid & 63;
  const int w = tid >> 6;          // 0..3 = wn
  const int l15 = lane & 15, l4 = lane >> 4;
  const int rowBase = blockIdx.x * 64;

  // ---- gather phase: rows w*16 .. w*16+15 ----
  for (int rr = 0; rr < 16; rr++) {
    int r = w * 16 + rr;
    int node = rowBase + r;
    if (K1 == 128) {
      float alo = 0.f, ahi = 0.f;
      if (node < N_NODES) {
        const unsigned int* xp = (const unsigned int*)X;
        unsigned int u = xp[(size_t)node * 64 + lane];
        alo = bf_lo(u); ahi = bf_hi(u);
        int s = csr[node], e = csr[node + 1];
        int i = s;
        for (; i + 4 <= e; i += 4) {
          int n0 = ssrc[i], n1 = ssrc[i + 1], n2 = ssrc[i + 2], n3 = ssrc[i + 3];
          unsigned int v0 = xp[(size_t)n0 * 64 + lane];
          unsigned int v1 = xp[(size_t)n1 * 64 + lane];
          unsigned int v2 = xp[(size_t)n2 * 64 + lane];
          unsigned int v3 = xp[(size_t)n3 * 64 + lane];
          alo += bf_lo(v0) + bf_lo(v1) + bf_lo(v2) + bf_lo(v3);
          ahi += bf_hi(v0) + bf_hi(v1) + bf_hi(v2) + bf_hi(v3);
        }
        for (; i < e; i++) {
          unsigned int v = xp[(size_t)ssrc[i] * 64 + lane];
          alo += bf_lo(v); ahi += bf_hi(v);
        }
      }
      // lane covers k = 2*lane, 2*lane+1
      *(unsigned int*)&AslF[((lane >> 2) * 64 + r) * 8 + 2 * (lane & 3)] = packbf(alo, ahi);
    } else {
      float a0 = 0.f, a1 = 0.f, a2 = 0.f, a3 = 0.f;
      if (node < N_NODES) {
        const uint2* xp = (const uint2*)X;
        uint2 u = xp[(size_t)node * 64 + lane];
        a0 = bf_lo(u.x); a1 = bf_hi(u.x); a2 = bf_lo(u.y); a3 = bf_hi(u.y);
        int s = csr[node], e = csr[node + 1];
        int i = s;
        for (; i + 4 <= e; i += 4) {
          int n0 = ssrc[i], n1 = ssrc[i + 1], n2 = ssrc[i + 2], n3 = ssrc[i + 3];
          uint2 v0 = xp[(size_t)n0 * 64 + lane];
          uint2 v1 = xp[(size_t)n1 * 64 + lane];
          uint2 v2 = xp[(size_t)n2 * 64 + lane];
          uint2 v3 = xp[(size_t)n3 * 64 + lane];
          a0 += bf_lo(v0.x) + bf_lo(v1.x) + bf_lo(v2.x) + bf_lo(v3.x);
          a1 += bf_hi(v0.x) + bf_hi(v1.x) + bf_hi(v2.x) + bf_hi(v3.x);
          a2 += bf_lo(v0.y) + bf_lo(v1.y) + bf_lo(v2.y) + bf_lo(v3.y);
          a3 += bf_hi(v0.y) + bf_hi(v1.y) + bf_hi(v2.y) + bf_hi(v3.y);
        }
        for (; i < e; i++) {
          uint2 v = xp[(size_t)ssrc[i] * 64 + lane];
          a0 += bf_lo(v.x); a1 += bf_hi(v.x);
          a2 += bf_lo(v.y); a3 += bf_hi(v.y);
        }
      }
      uint2 o;
      o.x = packbf(a0, a1);
      o.y = packbf(a2, a3);
      // lane covers k = 4*lane .. 4*lane+3
      *(uint2*)&AslF[((lane >> 1) * 64 + r) * 8 + 4 * (lane & 1)] = o;
    }
  }
  __syncthreads();

  // ---- GEMM1: h1 = relu(A @ W1 + b1) ----
  f32x4 acc[4][4] = {};
  for (int k0 = 0; k0 < K1; k0 += 32) {
#pragma unroll
    for (int i = 0; i < 4; i++) {
      int c = i * 256 + tid;
      int ko = c >> 8, n = c & 255;
      gload16(&W1t[(size_t)n * K1 + k0 + ko * 8], &Wsl[(size_t)(i * 256 + w * 64) * 8]);
    }
    __syncthreads();
    int koA = (k0 >> 3) + l4;
    bf16x8 a[4], b[4];
#pragma unroll
    for (int f = 0; f < 4; f++) {
      a[f] = *(const bf16x8*)&AslF[(size_t)(koA * 64 + f * 16 + l15) * 8];
      b[f] = *(const bf16x8*)&Wsl[(size_t)(l4 * 256 + w * 64 + f * 16 + l15) * 8];
    }
#pragma unroll
    for (int fm = 0; fm < 4; fm++)
#pragma unroll
      for (int fn = 0; fn < 4; fn++)
        acc[fm][fn] = __builtin_amdgcn_mfma_f32_16x16x32_bf16(a[fm], b[fn], acc[fm][fn], 0, 0, 0);
    __syncthreads();
  }

  // ---- h1 -> LDS (relu + bias, bf16), fragment layout ----
#pragma unroll
  for (int fm = 0; fm < 4; fm++) {
#pragma unroll
    for (int fn = 0; fn < 4; fn++) {
      int col = w * 64 + fn * 16 + l15;
      float bb = b1[col];
      int ko = col >> 3, kc = col & 7;
#pragma unroll
      for (int j = 0; j < 4; j++) {
        int r = fm * 16 + l4 * 4 + j;
        float v = fmaxf(acc[fm][fn][j] + bb, 0.f);
        Hsl[(size_t)(ko * 64 + r) * 8 + kc] = f2bf(v);
      }
      acc[fm][fn] = (f32x4){0.f, 0.f, 0.f, 0.f};
    }
  }
  __syncthreads();

  // ---- GEMM2: C = h1 @ W2 + b2 (optional relu) ----
  for (int k0 = 0; k0 < 256; k0 += 32) {
#pragma unroll
    for (int i = 0; i < 4; i++) {
      int c = i * 256 + tid;
      int ko = c >> 8, n = c & 255;
      gload16(&W2t[(size_t)n * 256 + k0 + ko * 8], &Wsl[(size_t)(i * 256 + w * 64) * 8]);
    }
    __syncthreads();
    int koA = (k0 >> 3) + l4;
    bf16x8 a[4], b[4];
#pragma unroll
    for (int f = 0; f < 4; f++) {
      a[f] = *(const bf16x8*)&Hsl[(size_t)(koA * 64 + f * 16 + l15) * 8];
      b[f] = *(const bf16x8*)&Wsl[(size_t)(l4 * 256 + w * 64 + f * 16 + l15) * 8];
    }
#pragma unroll
    for (int fm = 0; fm < 4; fm++)
#pragma unroll
      for (int fn = 0; fn < 4; fn++)
        acc[fm][fn] = __builtin_amdgcn_mfma_f32_16x16x32_bf16(a[fm], b[fn], acc[fm][fn], 0, 0, 0);
    __syncthreads();
  }

  // ---- epilogue ----
#pragma unroll
  for (int fm = 0; fm < 4; fm++) {
    int r0 = rowBase + fm * 16 + l4 * 4;
#pragma unroll
    for (int fn = 0; fn < 4; fn++) {
      int col = w * 64 + fn * 16 + l15;
      float bb = b2[col];
#pragma unroll
      for (int j = 0; j < 4; j++) {
        int r = r0 + j;
        if (r < N_NODES) {
          float v = acc[fm][fn][j] + bb;
          if (RELU2) v = fmaxf(v, 0.f);
          C[(size_t)r * HID + col] = f2bf(v);
        }
      }
    }
  }
}

// ---------------- pooling ----------------

__global__ __launch_bounds__(256) void pool_kernel(const unsigned short* __restrict__ H,
                                                   const int* __restrict__ batch,
                                                   float* __restrict__ sums,
                                                   float* __restrict__ cnts) {
  int d = threadIdx.x;
  int n0 = blockIdx.x * 128;
  int n1 = n0 + 128; if (n1 > N_NODES) n1 = N_NODES;
  int cur = batch[n0];
  float run = 0.f, runc = 0.f;
  for (int i = n0; i < n1; i++) {
    int b = batch[i];
    if (b != cur) {
      atomicAdd(&sums[(size_t)cur * HID + d], run);
      if (d == 0) atomicAdd(&cnts[cur], runc);
      run = 0.f; runc = 0.f; cur = b;
    }
    run += __uint_as_float(((unsigned int)H[(size_t)i * HID + d]) << 16);
    runc += 1.f;
  }
  atomicAdd(&sums[(size_t)cur * HID + d], run);
  if (d == 0) atomicAdd(&cnts[cur], runc);
}

// ---------------- head ----------------

__global__ __launch_bounds__(256) void head_kernel(const float* __restrict__ sums,
                                                   const float* __restrict__ cnts,
                                                   const float* __restrict__ gattr,
                                                   const float* __restrict__ wf1,
                                                   const float* __restrict__ bf1,
                                                   const float* __restrict__ wf2,
                                                   const float* __restrict__ bf2,
                                                   float* __restrict__ out) {
  int g = blockIdx.x, tid = threadIdx.x;
  __shared__ float gv[HID + GA];
  __shared__ float red[256];
  float c = cnts[g]; c = fmaxf(c, 1.0f);
  gv[tid] = sums[(size_t)g * HID + tid] / c;
  if (tid < GA) gv[HID + tid] = gattr[g * GA + tid];
  __syncthreads();
  float acc = bf1[tid];
  for (int k = 0; k < HID + GA; k++)
    acc = fmaf(gv[k], wf1[(size_t)k * HID + tid], acc);
  float h = fmaxf(acc, 0.f);
  red[tid] = h * wf2[tid];
  __syncthreads();
  for (int s = 128; s > 0; s >>= 1) {
    if (tid < s) red[tid] += red[tid + s];
    __syncthreads();
  }
  if (tid == 0) out[g] = red[0] + bf2[0];
}

// ---------------- launch ----------------

extern "C" void kernel_launch(void* const* d_in, const int* in_sizes, int n_in,
                              void* d_out, int out_size, void* d_ws, size_t ws_size,
                              hipStream_t stream) {
  const float* x     = (const float*)d_in[0];
  const int*   eidx  = (const int*)d_in[1];
  const int*   batch = (const int*)d_in[2];
  const float* gattr = (const float*)d_in[3];
  const float* w1a = (const float*)d_in[4];  const float* b1a = (const float*)d_in[5];
  const float* w1b = (const float*)d_in[6];  const float* b1b = (const float*)d_in[7];
  const float* w2a = (const float*)d_in[8];  const float* b2a = (const float*)d_in[9];
  const float* w2b = (const float*)d_in[10]; const float* b2b = (const float*)d_in[11];
  const float* wf1 = (const float*)d_in[12]; const float* bf1 = (const float*)d_in[13];
  const float* wf2 = (const float*)d_in[14]; const float* bf2 = (const float*)d_in[15];
  float* out = (float*)d_out;

  const int* esrc = eidx;
  const int* edst = eidx + N_EDGES;

  char* w = (char*)d_ws;
  auto alloc = [&](size_t bytes) -> void* {
    void* p = (void*)w;
    w += (bytes + 255) & ~(size_t)255;
    return p;
  };
  unsigned short* B0 = (unsigned short*)alloc((size_t)N_NODES * DIN * 2);  // x bf16
  unsigned short* B1 = (unsigned short*)alloc((size_t)N_NODES * HID * 2);  // conv1 out
  unsigned short* B2 = (unsigned short*)alloc((size_t)N_NODES * HID * 2);  // conv2 out
  unsigned short* w1aT = (unsigned short*)alloc(256 * 128 * 2);
  unsigned short* w1bT = (unsigned short*)alloc(256 * 256 * 2);
  unsigned short* w2aT = (unsigned short*)alloc(256 * 256 * 2);
  unsigned short* w2bT = (unsigned short*)alloc(256 * 256 * 2);
  int*   csr    = (int*)alloc((N_NODES + 4) * 4);
  int*   cursor = (int*)alloc(NBUCK * 4);
  unsigned int* tmp = (unsigned int*)alloc((size_t)NBUCK * BCAP * 4);
  int*   ssrc   = (int*)alloc((size_t)N_EDGES * 4);
  float* sums   = (float*)alloc((size_t)NGRAPH * HID * 4);
  float* cnts   = (float*)alloc(NGRAPH * 4);

  hipMemsetAsync(cursor, 0, NBUCK * 4, stream);
  hipMemsetAsync(sums, 0, (size_t)NGRAPH * HID * 4 + 256, stream);  // sums + cnts

  cvt_x_kernel<<<12500, 256, 0, stream>>>(x, B0);
  cvt_w_all<<<896, 256, 0, stream>>>(w1a, w1b, w2a, w2b, w1aT, w1bT, w2aT, w2bT);

  bin_kernel<<<(N_EDGES + 4095) / 4096, 256, 0, stream>>>(esrc, edst, cursor, tmp);
  sort_kernel<<<NBUCK, 512, 0, stream>>>(tmp, cursor, csr, ssrc);

  const int nconv = (N_NODES + 63) / 64;
  conv_fused<128, true><<<nconv, 256, 0, stream>>>(B0, csr, ssrc, w1aT, b1a, w1bT, b1b, B1);
  conv_fused<256, false><<<nconv, 256, 0, stream>>>(B1, csr, ssrc, w2aT, b2a, w2bT, b2b, B2);

  pool_kernel<<<(N_NODES + 127) / 128, 256, 0, stream>>>(B2, batch, sums, cnts);
  head_kernel<<<NGRAPH, 256, 0, stream>>>(sums, cnts, gattr, wf1, bf1, wf2, bf2, out);
}

// Round 5
// 515.605 us; speedup vs baseline: 1.3782x; 1.3782x over previous
//
#include <hip/hip_runtime.h>

#define N_NODES 100000
#define N_EDGES 1600000
#define NGRAPH  64
#define DIN     128
#define HID     256
#define GA      6

// bucketed CSR build
#define NBUCK  98        // ceil(100000 / 1024)
#define BSHIFT 10        // 1024 nodes per bucket
#define BCAP   20480     // per-bucket capacity (mean 16384, +32 sigma)

typedef __attribute__((ext_vector_type(8))) short bf16x8;
typedef __attribute__((ext_vector_type(4))) float f32x4;

__device__ __forceinline__ unsigned short f2bf(float f) {
  unsigned int u = __float_as_uint(f);
  u += 0x7fffu + ((u >> 16) & 1u);
  return (unsigned short)(u >> 16);
}
__device__ __forceinline__ float bf_lo(unsigned int u) { return __uint_as_float(u << 16); }
__device__ __forceinline__ float bf_hi(unsigned int u) { return __uint_as_float(u & 0xffff0000u); }
__device__ __forceinline__ unsigned int packbf(float lo, float hi) {
  return (unsigned int)f2bf(lo) | ((unsigned int)f2bf(hi) << 16);
}

__device__ __forceinline__ void gload16(const void* g, void* l) {
  __builtin_amdgcn_global_load_lds(
      (const __attribute__((address_space(1))) unsigned int*)g,
      (__attribute__((address_space(3))) unsigned int*)l, 16, 0, 0);
}

// ---------------- prep: f32 -> bf16 conversions ----------------

__global__ __launch_bounds__(256) void cvt_x_kernel(const float* __restrict__ in,
                                                    unsigned short* __restrict__ out) {
  size_t idx = ((size_t)blockIdx.x * 256 + threadIdx.x) * 4;  // 12.8M total, exact
  float4 v = *(const float4*)&in[idx];
  ushort4 o;
  o.x = f2bf(v.x); o.y = f2bf(v.y); o.z = f2bf(v.z); o.w = f2bf(v.w);
  *(ushort4*)&out[idx] = o;
}

// all four weight transposes in one launch: out[n*K+k] = bf16(in[k*256+n])
__global__ __launch_bounds__(256) void cvt_w_all(const float* __restrict__ w1a,
                                                 const float* __restrict__ w1b,
                                                 const float* __restrict__ w2a,
                                                 const float* __restrict__ w2b,
                                                 unsigned short* __restrict__ o1a,
                                                 unsigned short* __restrict__ o1b,
                                                 unsigned short* __restrict__ o2a,
                                                 unsigned short* __restrict__ o2b) {
  int bid = blockIdx.x, tid = threadIdx.x;
  const float* in; unsigned short* out; int shift, idx;
  if (bid < 128)      { in = w1a; out = o1a; shift = 7; idx = bid * 256 + tid; }
  else if (bid < 384) { in = w1b; out = o1b; shift = 8; idx = (bid - 128) * 256 + tid; }
  else if (bid < 640) { in = w2a; out = o2a; shift = 8; idx = (bid - 384) * 256 + tid; }
  else                { in = w2b; out = o2b; shift = 8; idx = (bid - 640) * 256 + tid; }
  int K = 1 << shift;
  int n = idx >> shift;
  int k = idx & (K - 1);
  out[idx] = f2bf(in[(size_t)k * HID + n]);
}

// ---------------- pass 1: bin edges by dst>>10 with block-local sort ----------------

__global__ __launch_bounds__(256) void bin_kernel(const int* __restrict__ esrc,
                                                  const int* __restrict__ edst,
                                                  int* __restrict__ cursor,
                                                  unsigned int* __restrict__ tmp) {
  __shared__ unsigned int pk[4096];
  __shared__ int hist[NBUCK], lbase[NBUCK + 1], gbase[NBUCK], lcur[NBUCK];
  const int tid = threadIdx.x;
  const int lane = tid & 63;
  const int ebase = blockIdx.x * 4096;
  const int n = min(4096, N_EDGES - ebase);
  if (tid < NBUCK) hist[tid] = 0;
  __syncthreads();
  unsigned int pkv[16]; int bk[16];
#pragma unroll
  for (int i = 0; i < 16; i++) {
    int e = ebase + i * 256 + tid;
    bk[i] = -1;
    if (e < N_EDGES) {
      int s = esrc[e], d = edst[e];
      bk[i] = d >> BSHIFT;
      pkv[i] = (unsigned int)s | ((unsigned int)(d & ((1 << BSHIFT) - 1)) << 17);
      atomicAdd(&hist[bk[i]], 1);
    }
  }
  __syncthreads();
  if (tid < 64) {
    int i0 = 2 * tid, i1 = i0 + 1;
    int a0 = (i0 < NBUCK) ? hist[i0] : 0;
    int a1 = (i1 < NBUCK) ? hist[i1] : 0;
    int p = a0 + a1, sc = p;
#pragma unroll
    for (int off = 1; off < 64; off <<= 1) {
      int t = __shfl_up(sc, off);
      if (lane >= off) sc += t;
    }
    int excl = sc - p;
    if (i0 < NBUCK) lbase[i0] = excl;
    if (i1 < NBUCK) lbase[i1] = excl + a0;
    if (tid == 63) lbase[NBUCK] = sc;
  }
  __syncthreads();
  if (tid < NBUCK) {
    int c = hist[tid];
    gbase[tid] = c ? atomicAdd(&cursor[tid], c) : 0;
    lcur[tid] = lbase[tid];
  }
  __syncthreads();
#pragma unroll
  for (int i = 0; i < 16; i++) {
    if (bk[i] >= 0) {
      int pos = atomicAdd(&lcur[bk[i]], 1);
      pk[pos] = pkv[i];
    }
  }
  __syncthreads();
#pragma unroll
  for (int i = 0; i < 16; i++) {
    int idx = i * 256 + tid;
    if (idx < n) {
      int lo = 0, hi = NBUCK;
      while (hi - lo > 1) {
        int mid = (lo + hi) >> 1;
        if (lbase[mid] <= idx) lo = mid; else hi = mid;
      }
      tmp[(size_t)lo * BCAP + gbase[lo] + (idx - lbase[lo])] = pk[idx];
    }
  }
}

// ---------------- pass 2: per-bucket counting sort -> csr + ssrc ----------------

__global__ __launch_bounds__(512) void sort_kernel(const unsigned int* __restrict__ tmp,
                                                   const int* __restrict__ cnt,
                                                   int* __restrict__ csr,
                                                   int* __restrict__ ssrc) {
  __shared__ int nhist[1024], ncur[1024];
  __shared__ int bb[NBUCK];
  __shared__ int wsum[8];
  const int b = blockIdx.x;
  const int tid = threadIdx.x;
  const int lane = tid & 63, wid = tid >> 6;
  if (tid < 64) {
    int i0 = 2 * tid, i1 = i0 + 1;
    int a0 = (i0 < NBUCK) ? cnt[i0] : 0;
    int a1 = (i1 < NBUCK) ? cnt[i1] : 0;
    int p = a0 + a1, sc = p;
#pragma unroll
    for (int off = 1; off < 64; off <<= 1) {
      int t = __shfl_up(sc, off);
      if (lane >= off) sc += t;
    }
    int excl = sc - p;
    if (i0 < NBUCK) bb[i0] = excl;
    if (i1 < NBUCK) bb[i1] = excl + a0;
  }
  nhist[tid] = 0; nhist[tid + 512] = 0;
  __syncthreads();
  const int myCnt = cnt[b];
  const int ebase = bb[b];
  const unsigned int* srcp = tmp + (size_t)b * BCAP;
  for (int i = tid; i < myCnt; i += 512)
    atomicAdd(&nhist[srcp[i] >> 17], 1);
  __syncthreads();
  int i0 = 2 * tid;
  int a0 = nhist[i0], a1 = nhist[i0 + 1];
  int p = a0 + a1, sc = p;
#pragma unroll
  for (int off = 1; off < 64; off <<= 1) {
    int t = __shfl_up(sc, off);
    if (lane >= off) sc += t;
  }
  if (lane == 63) wsum[wid] = sc;
  __syncthreads();
  if (tid < 8) {
    int ws = wsum[tid];
#pragma unroll
    for (int off = 1; off < 8; off <<= 1) {
      int t = __shfl_up(ws, off);
      if (tid >= off) ws += t;
    }
    wsum[tid] = ws;
  }
  __syncthreads();
  int excl = ((wid > 0) ? wsum[wid - 1] : 0) + sc - p;
  ncur[i0] = excl;
  ncur[i0 + 1] = excl + a0;
  int node0 = (b << BSHIFT) + i0;
  if (node0 < N_NODES) csr[node0] = ebase + excl;
  if (node0 + 1 < N_NODES) csr[node0 + 1] = ebase + excl + a0;
  if (b == 0 && tid == 0) csr[N_NODES] = N_EDGES;
  __syncthreads();
  for (int i = tid; i < myCnt; i += 512) {
    unsigned int pe = srcp[i];
    int pos = atomicAdd(&ncur[pe >> 17], 1);
    ssrc[ebase + pos] = (int)(pe & 0x1FFFF);
  }
}

// ---------------- aggregation (bf16 in/out, f32 accum) — skinny, high-occupancy ----------------

__global__ __launch_bounds__(256) void agg1_kernel(const unsigned int* __restrict__ x,
                                                   const int* __restrict__ csr,
                                                   const int* __restrict__ ssrc,
                                                   unsigned int* __restrict__ out) {
  int node = blockIdx.x * 4 + (threadIdx.x >> 6);
  int lane = threadIdx.x & 63;
  unsigned int u = x[(size_t)node * 64 + lane];
  float alo = bf_lo(u), ahi = bf_hi(u);
  int s = csr[node], e = csr[node + 1];
  int i = s;
  for (; i + 4 <= e; i += 4) {
    int n0 = ssrc[i], n1 = ssrc[i + 1], n2 = ssrc[i + 2], n3 = ssrc[i + 3];
    unsigned int v0 = x[(size_t)n0 * 64 + lane];
    unsigned int v1 = x[(size_t)n1 * 64 + lane];
    unsigned int v2 = x[(size_t)n2 * 64 + lane];
    unsigned int v3 = x[(size_t)n3 * 64 + lane];
    alo += bf_lo(v0) + bf_lo(v1) + bf_lo(v2) + bf_lo(v3);
    ahi += bf_hi(v0) + bf_hi(v1) + bf_hi(v2) + bf_hi(v3);
  }
  for (; i < e; i++) {
    unsigned int v = x[(size_t)ssrc[i] * 64 + lane];
    alo += bf_lo(v); ahi += bf_hi(v);
  }
  out[(size_t)node * 64 + lane] = packbf(alo, ahi);
}

__global__ __launch_bounds__(256) void agg2_kernel(const uint2* __restrict__ x,
                                                   const int* __restrict__ csr,
                                                   const int* __restrict__ ssrc,
                                                   uint2* __restrict__ out) {
  int node = blockIdx.x * 4 + (threadIdx.x >> 6);
  int lane = threadIdx.x & 63;
  uint2 u = x[(size_t)node * 64 + lane];
  float a0 = bf_lo(u.x), a1 = bf_hi(u.x), a2 = bf_lo(u.y), a3 = bf_hi(u.y);
  int s = csr[node], e = csr[node + 1];
  int i = s;
  for (; i + 4 <= e; i += 4) {
    int n0 = ssrc[i], n1 = ssrc[i + 1], n2 = ssrc[i + 2], n3 = ssrc[i + 3];
    uint2 v0 = x[(size_t)n0 * 64 + lane];
    uint2 v1 = x[(size_t)n1 * 64 + lane];
    uint2 v2 = x[(size_t)n2 * 64 + lane];
    uint2 v3 = x[(size_t)n3 * 64 + lane];
    a0 += bf_lo(v0.x) + bf_lo(v1.x) + bf_lo(v2.x) + bf_lo(v3.x);
    a1 += bf_hi(v0.x) + bf_hi(v1.x) + bf_hi(v2.x) + bf_hi(v3.x);
    a2 += bf_lo(v0.y) + bf_lo(v1.y) + bf_lo(v2.y) + bf_lo(v3.y);
    a3 += bf_hi(v0.y) + bf_hi(v1.y) + bf_hi(v2.y) + bf_hi(v3.y);
  }
  for (; i < e; i++) {
    uint2 v = x[(size_t)ssrc[i] * 64 + lane];
    a0 += bf_lo(v.x); a1 += bf_hi(v.x);
    a2 += bf_lo(v.y); a3 += bf_hi(v.y);
  }
  uint2 o;
  o.x = packbf(a0, a1);
  o.y = packbf(a2, a3);
  out[(size_t)node * 64 + lane] = o;
}

// ---------------- fused MLP: C = [relu](relu(A@W1+b1)@W2+b2), no gather ----------------
// A [N][K1] bf16 (agg output, coalesced reads); W1t [256][K1], W2t [256][256] bf16.
// Block 256 thr (4 waves = 4 col-groups), 64-row tile, BK=32.
// h1 (64x256 bf16) in LDS, XOR-swizzled row-major: byte ^= (row&7)<<4.
//   write: shfl-paired dword writes -> 2-way (free); read: ds_read_b128 bank-balanced.
template<int K1, bool RELU2>
__global__ __launch_bounds__(256, 3)
void mlp_fused(const unsigned short* __restrict__ A,
               const unsigned short* __restrict__ W1t,
               const float* __restrict__ b1,
               const unsigned short* __restrict__ W2t,
               const float* __restrict__ b2,
               unsigned short* __restrict__ C) {
  __shared__ unsigned short Asl[4 * 64 * 8];    //  4 KB: [ko][row][8]
  __shared__ unsigned short Wsl[4 * 256 * 8];   // 16 KB: [ko][n][8]
  __shared__ unsigned short Hsl[64 * 256];      // 32 KB: swizzled row-major

  const int tid = threadIdx.x;
  const int lane = tid & 63;
  const int wn = tid >> 6;        // 0..3
  const int l15 = lane & 15, l4 = lane >> 4;
  const int rowBase = blockIdx.x * 64;

  f32x4 acc[4][4] = {};

  // ---- GEMM1: h1 = relu(A @ W1 + b1) ----
  for (int k0 = 0; k0 < K1; k0 += 32) {
    {  // stage A tile 64x32 (4 KB): chunk c=tid -> ko=c>>6, m=c&63 (LDS linear in tid)
      int ko = tid >> 6, m = tid & 63;
      int gr = rowBase + m; if (gr >= N_NODES) gr = N_NODES - 1;
      gload16(&A[(size_t)gr * K1 + k0 + ko * 8], &Asl[(size_t)tid * 8]);
    }
#pragma unroll
    for (int i = 0; i < 4; i++) {  // stage W1 tile 32x256 (16 KB)
      int c = i * 256 + tid;
      int ko = c >> 8, n = c & 255;
      gload16(&W1t[(size_t)n * K1 + k0 + ko * 8], &Wsl[(size_t)(i * 256 + wn * 64) * 8]);
    }
    __syncthreads();
    bf16x8 a[4], b[4];
#pragma unroll
    for (int f = 0; f < 4; f++) {
      a[f] = *(const bf16x8*)&Asl[(size_t)(l4 * 64 + f * 16 + l15) * 8];
      b[f] = *(const bf16x8*)&Wsl[(size_t)(l4 * 256 + wn * 64 + f * 16 + l15) * 8];
    }
#pragma unroll
    for (int fm = 0; fm < 4; fm++)
#pragma unroll
      for (int fn = 0; fn < 4; fn++)
        acc[fm][fn] = __builtin_amdgcn_mfma_f32_16x16x32_bf16(a[fm], b[fn], acc[fm][fn], 0, 0, 0);
    __syncthreads();
  }

  // ---- h1 -> swizzled LDS (bias + relu), paired dword writes ----
#pragma unroll
  for (int fm = 0; fm < 4; fm++) {
#pragma unroll
    for (int fn = 0; fn < 4; fn++) {
      int col = wn * 64 + fn * 16 + l15;
      float bb = b1[col];
#pragma unroll
      for (int j = 0; j < 4; j++) {
        int r = fm * 16 + l4 * 4 + j;
        float v = fmaxf(acc[fm][fn][j] + bb, 0.f);
        float pv = __shfl_xor(v, 1);
        if ((l15 & 1) == 0) {
          unsigned int off = ((unsigned int)(r * 256 + col) * 2) ^ ((unsigned int)(r & 7) << 4);
          *(unsigned int*)((char*)Hsl + off) = packbf(v, pv);
        }
      }
      acc[fm][fn] = (f32x4){0.f, 0.f, 0.f, 0.f};
    }
  }
  __syncthreads();

  // ---- GEMM2: C = h1 @ W2 + b2 ----
  for (int k0 = 0; k0 < 256; k0 += 32) {
#pragma unroll
    for (int i = 0; i < 4; i++) {
      int c = i * 256 + tid;
      int ko = c >> 8, n = c & 255;
      gload16(&W2t[(size_t)n * 256 + k0 + ko * 8], &Wsl[(size_t)(i * 256 + wn * 64) * 8]);
    }
    __syncthreads();
    bf16x8 a[4], b[4];
    int koA = (k0 >> 3) + l4;
#pragma unroll
    for (int f = 0; f < 4; f++) {
      int row = f * 16 + l15;
      unsigned int off = ((unsigned int)(row * 256 + koA * 8) * 2) ^ ((unsigned int)(row & 7) << 4);
      a[f] = *(const bf16x8*)((char*)Hsl + off);
      b[f] = *(const bf16x8*)&Wsl[(size_t)(l4 * 256 + wn * 64 + f * 16 + l15) * 8];
    }
#pragma unroll
    for (int fm = 0; fm < 4; fm++)
#pragma unroll
      for (int fn = 0; fn < 4; fn++)
        acc[fm][fn] = __builtin_amdgcn_mfma_f32_16x16x32_bf16(a[fm], b[fn], acc[fm][fn], 0, 0, 0);
    __syncthreads();
  }

  // ---- epilogue ----
#pragma unroll
  for (int fm = 0; fm < 4; fm++) {
    int r0 = rowBase + fm * 16 + l4 * 4;
#pragma unroll
    for (int fn = 0; fn < 4; fn++) {
      int col = wn * 64 + fn * 16 + l15;
      float bb = b2[col];
#pragma unroll
      for (int j = 0; j < 4; j++) {
        int r = r0 + j;
        if (r < N_NODES) {
          float v = acc[fm][fn][j] + bb;
          if (RELU2) v = fmaxf(v, 0.f);
          C[(size_t)r * HID + col] = f2bf(v);
        }
      }
    }
  }
}

// ---------------- pooling ----------------

__global__ __launch_bounds__(256) void pool_kernel(const unsigned short* __restrict__ H,
                                                   const int* __restrict__ batch,
                                                   float* __restrict__ sums,
                                                   float* __restrict__ cnts) {
  int d = threadIdx.x;
  int n0 = blockIdx.x * 128;
  int n1 = n0 + 128; if (n1 > N_NODES) n1 = N_NODES;
  int cur = batch[n0];
  float run = 0.f, runc = 0.f;
  for (int i = n0; i < n1; i++) {
    int b = batch[i];
    if (b != cur) {
      atomicAdd(&sums[(size_t)cur * HID + d], run);
      if (d == 0) atomicAdd(&cnts[cur], runc);
      run = 0.f; runc = 0.f; cur = b;
    }
    run += __uint_as_float(((unsigned int)H[(size_t)i * HID + d]) << 16);
    runc += 1.f;
  }
  atomicAdd(&sums[(size_t)cur * HID + d], run);
  if (d == 0) atomicAdd(&cnts[cur], runc);
}

// ---------------- head ----------------

__global__ __launch_bounds__(256) void head_kernel(const float* __restrict__ sums,
                                                   const float* __restrict__ cnts,
                                                   const float* __restrict__ gattr,
                                                   const float* __restrict__ wf1,
                                                   const float* __restrict__ bf1,
                                                   const float* __restrict__ wf2,
                                                   const float* __restrict__ bf2,
                                                   float* __restrict__ out) {
  int g = blockIdx.x, tid = threadIdx.x;
  __shared__ float gv[HID + GA];
  __shared__ float red[256];
  float c = cnts[g]; c = fmaxf(c, 1.0f);
  gv[tid] = sums[(size_t)g * HID + tid] / c;
  if (tid < GA) gv[HID + tid] = gattr[g * GA + tid];
  __syncthreads();
  float acc = bf1[tid];
  for (int k = 0; k < HID + GA; k++)
    acc = fmaf(gv[k], wf1[(size_t)k * HID + tid], acc);
  float h = fmaxf(acc, 0.f);
  red[tid] = h * wf2[tid];
  __syncthreads();
  for (int s = 128; s > 0; s >>= 1) {
    if (tid < s) red[tid] += red[tid + s];
    __syncthreads();
  }
  if (tid == 0) out[g] = red[0] + bf2[0];
}

// ---------------- launch ----------------

extern "C" void kernel_launch(void* const* d_in, const int* in_sizes, int n_in,
                              void* d_out, int out_size, void* d_ws, size_t ws_size,
                              hipStream_t stream) {
  const float* x     = (const float*)d_in[0];
  const int*   eidx  = (const int*)d_in[1];
  const int*   batch = (const int*)d_in[2];
  const float* gattr = (const float*)d_in[3];
  const float* w1a = (const float*)d_in[4];  const float* b1a = (const float*)d_in[5];
  const float* w1b = (const float*)d_in[6];  const float* b1b = (const float*)d_in[7];
  const float* w2a = (const float*)d_in[8];  const float* b2a = (const float*)d_in[9];
  const float* w2b = (const float*)d_in[10]; const float* b2b = (const float*)d_in[11];
  const float* wf1 = (const float*)d_in[12]; const float* bf1 = (const float*)d_in[13];
  const float* wf2 = (const float*)d_in[14]; const float* bf2 = (const float*)d_in[15];
  float* out = (float*)d_out;

  const int* esrc = eidx;
  const int* edst = eidx + N_EDGES;

  char* w = (char*)d_ws;
  auto alloc = [&](size_t bytes) -> void* {
    void* p = (void*)w;
    w += (bytes + 255) & ~(size_t)255;
    return p;
  };
  unsigned short* B0 = (unsigned short*)alloc((size_t)N_NODES * DIN * 2);  // x bf16
  unsigned short* B1 = (unsigned short*)alloc((size_t)N_NODES * HID * 2);
  unsigned short* B2 = (unsigned short*)alloc((size_t)N_NODES * HID * 2);
  unsigned short* w1aT = (unsigned short*)alloc(256 * 128 * 2);
  unsigned short* w1bT = (unsigned short*)alloc(256 * 256 * 2);
  unsigned short* w2aT = (unsigned short*)alloc(256 * 256 * 2);
  unsigned short* w2bT = (unsigned short*)alloc(256 * 256 * 2);
  int*   csr    = (int*)alloc((N_NODES + 4) * 4);
  int*   cursor = (int*)alloc(NBUCK * 4);
  unsigned int* tmp = (unsigned int*)alloc((size_t)NBUCK * BCAP * 4);
  int*   ssrc   = (int*)alloc((size_t)N_EDGES * 4);
  float* sums   = (float*)alloc((size_t)NGRAPH * HID * 4);
  float* cnts   = (float*)alloc(NGRAPH * 4);

  hipMemsetAsync(cursor, 0, NBUCK * 4, stream);
  hipMemsetAsync(sums, 0, (size_t)NGRAPH * HID * 4 + 256, stream);  // sums + cnts

  cvt_x_kernel<<<12500, 256, 0, stream>>>(x, B0);
  cvt_w_all<<<896, 256, 0, stream>>>(w1a, w1b, w2a, w2b, w1aT, w1bT, w2aT, w2bT);

  bin_kernel<<<(N_EDGES + 4095) / 4096, 256, 0, stream>>>(esrc, edst, cursor, tmp);
  sort_kernel<<<NBUCK, 512, 0, stream>>>(tmp, cursor, csr, ssrc);

  const int nconv = (N_NODES + 63) / 64;
  // conv1: agg (x bf16) -> B1[N][128]; MLP -> B2
  agg1_kernel<<<N_NODES / 4, 256, 0, stream>>>((const unsigned int*)B0, csr, ssrc,
                                               (unsigned int*)B1);
  mlp_fused<128, true><<<nconv, 256, 0, stream>>>(B1, w1aT, b1a, w1bT, b1b, B2);
  // conv2: agg (B2) -> B1[N][256]; MLP -> B2
  agg2_kernel<<<N_NODES / 4, 256, 0, stream>>>((const uint2*)B2, csr, ssrc, (uint2*)B1);
  mlp_fused<256, false><<<nconv, 256, 0, stream>>>(B1, w2aT, b2a, w2bT, b2b, B2);

  pool_kernel<<<(N_NODES + 127) / 128, 256, 0, stream>>>(B2, batch, sums, cnts);
  head_kernel<<<NGRAPH, 256, 0, stream>>>(sums, cnts, gattr, wf1, bf1, wf2, bf2, out);
}

// Round 6
// 510.224 us; speedup vs baseline: 1.3928x; 1.0105x over previous
//
#include <hip/hip_runtime.h>

#define N_NODES 100000
#define N_EDGES 1600000
#define NGRAPH  64
#define DIN     128
#define HID     256
#define GA      6

// bucketed CSR build
#define NBUCK  98        // ceil(100000 / 1024)
#define BSHIFT 10        // 1024 nodes per bucket
#define BCAP   20480     // per-bucket capacity (mean 16384, +32 sigma)

typedef __attribute__((ext_vector_type(8))) short bf16x8;
typedef __attribute__((ext_vector_type(4))) float f32x4;

__device__ __forceinline__ unsigned short f2bf(float f) {
  unsigned int u = __float_as_uint(f);
  u += 0x7fffu + ((u >> 16) & 1u);
  return (unsigned short)(u >> 16);
}
__device__ __forceinline__ float bf_lo(unsigned int u) { return __uint_as_float(u << 16); }
__device__ __forceinline__ float bf_hi(unsigned int u) { return __uint_as_float(u & 0xffff0000u); }
__device__ __forceinline__ unsigned int packbf(float lo, float hi) {
  return (unsigned int)f2bf(lo) | ((unsigned int)f2bf(hi) << 16);
}

__device__ __forceinline__ void gload16(const void* g, void* l) {
  __builtin_amdgcn_global_load_lds(
      (const __attribute__((address_space(1))) unsigned int*)g,
      (__attribute__((address_space(3))) unsigned int*)l, 16, 0, 0);
}

// ---------------- prep: f32 -> bf16 conversions ----------------

__global__ __launch_bounds__(256) void cvt_x_kernel(const float* __restrict__ in,
                                                    unsigned short* __restrict__ out) {
  size_t idx = ((size_t)blockIdx.x * 256 + threadIdx.x) * 4;  // 12.8M total, exact
  float4 v = *(const float4*)&in[idx];
  ushort4 o;
  o.x = f2bf(v.x); o.y = f2bf(v.y); o.z = f2bf(v.z); o.w = f2bf(v.w);
  *(ushort4*)&out[idx] = o;
}

// all four weight transposes in one launch: out[n*K+k] = bf16(in[k*256+n])
__global__ __launch_bounds__(256) void cvt_w_all(const float* __restrict__ w1a,
                                                 const float* __restrict__ w1b,
                                                 const float* __restrict__ w2a,
                                                 const float* __restrict__ w2b,
                                                 unsigned short* __restrict__ o1a,
                                                 unsigned short* __restrict__ o1b,
                                                 unsigned short* __restrict__ o2a,
                                                 unsigned short* __restrict__ o2b) {
  int bid = blockIdx.x, tid = threadIdx.x;
  const float* in; unsigned short* out; int shift, idx;
  if (bid < 128)      { in = w1a; out = o1a; shift = 7; idx = bid * 256 + tid; }
  else if (bid < 384) { in = w1b; out = o1b; shift = 8; idx = (bid - 128) * 256 + tid; }
  else if (bid < 640) { in = w2a; out = o2a; shift = 8; idx = (bid - 384) * 256 + tid; }
  else                { in = w2b; out = o2b; shift = 8; idx = (bid - 640) * 256 + tid; }
  int K = 1 << shift;
  int n = idx >> shift;
  int k = idx & (K - 1);
  out[idx] = f2bf(in[(size_t)k * HID + n]);
}

// ---------------- pass 1: bin edges by dst>>10 with block-local sort ----------------

__global__ __launch_bounds__(256) void bin_kernel(const int* __restrict__ esrc,
                                                  const int* __restrict__ edst,
                                                  int* __restrict__ cursor,
                                                  unsigned int* __restrict__ tmp) {
  __shared__ unsigned int pk[4096];
  __shared__ int hist[NBUCK], lbase[NBUCK + 1], gbase[NBUCK], lcur[NBUCK];
  const int tid = threadIdx.x;
  const int lane = tid & 63;
  const int ebase = blockIdx.x * 4096;
  const int n = min(4096, N_EDGES - ebase);
  if (tid < NBUCK) hist[tid] = 0;
  __syncthreads();
  unsigned int pkv[16]; int bk[16];
#pragma unroll
  for (int i = 0; i < 16; i++) {
    int e = ebase + i * 256 + tid;
    bk[i] = -1;
    if (e < N_EDGES) {
      int s = esrc[e], d = edst[e];
      bk[i] = d >> BSHIFT;
      pkv[i] = (unsigned int)s | ((unsigned int)(d & ((1 << BSHIFT) - 1)) << 17);
      atomicAdd(&hist[bk[i]], 1);
    }
  }
  __syncthreads();
  if (tid < 64) {
    int i0 = 2 * tid, i1 = i0 + 1;
    int a0 = (i0 < NBUCK) ? hist[i0] : 0;
    int a1 = (i1 < NBUCK) ? hist[i1] : 0;
    int p = a0 + a1, sc = p;
#pragma unroll
    for (int off = 1; off < 64; off <<= 1) {
      int t = __shfl_up(sc, off);
      if (lane >= off) sc += t;
    }
    int excl = sc - p;
    if (i0 < NBUCK) lbase[i0] = excl;
    if (i1 < NBUCK) lbase[i1] = excl + a0;
    if (tid == 63) lbase[NBUCK] = sc;
  }
  __syncthreads();
  if (tid < NBUCK) {
    int c = hist[tid];
    gbase[tid] = c ? atomicAdd(&cursor[tid], c) : 0;
    lcur[tid] = lbase[tid];
  }
  __syncthreads();
#pragma unroll
  for (int i = 0; i < 16; i++) {
    if (bk[i] >= 0) {
      int pos = atomicAdd(&lcur[bk[i]], 1);
      pk[pos] = pkv[i];
    }
  }
  __syncthreads();
#pragma unroll
  for (int i = 0; i < 16; i++) {
    int idx = i * 256 + tid;
    if (idx < n) {
      int lo = 0, hi = NBUCK;
      while (hi - lo > 1) {
        int mid = (lo + hi) >> 1;
        if (lbase[mid] <= idx) lo = mid; else hi = mid;
      }
      tmp[(size_t)lo * BCAP + gbase[lo] + (idx - lbase[lo])] = pk[idx];
    }
  }
}

// ---------------- pass 2: per-bucket counting sort -> csr + ssrc ----------------

__global__ __launch_bounds__(512) void sort_kernel(const unsigned int* __restrict__ tmp,
                                                   const int* __restrict__ cnt,
                                                   int* __restrict__ csr,
                                                   int* __restrict__ ssrc) {
  __shared__ int nhist[1024], ncur[1024];
  __shared__ int bb[NBUCK];
  __shared__ int wsum[8];
  const int b = blockIdx.x;
  const int tid = threadIdx.x;
  const int lane = tid & 63, wid = tid >> 6;
  if (tid < 64) {
    int i0 = 2 * tid, i1 = i0 + 1;
    int a0 = (i0 < NBUCK) ? cnt[i0] : 0;
    int a1 = (i1 < NBUCK) ? cnt[i1] : 0;
    int p = a0 + a1, sc = p;
#pragma unroll
    for (int off = 1; off < 64; off <<= 1) {
      int t = __shfl_up(sc, off);
      if (lane >= off) sc += t;
    }
    int excl = sc - p;
    if (i0 < NBUCK) bb[i0] = excl;
    if (i1 < NBUCK) bb[i1] = excl + a0;
  }
  nhist[tid] = 0; nhist[tid + 512] = 0;
  __syncthreads();
  const int myCnt = cnt[b];
  const int ebase = bb[b];
  const unsigned int* srcp = tmp + (size_t)b * BCAP;
  for (int i = tid; i < myCnt; i += 512)
    atomicAdd(&nhist[srcp[i] >> 17], 1);
  __syncthreads();
  int i0 = 2 * tid;
  int a0 = nhist[i0], a1 = nhist[i0 + 1];
  int p = a0 + a1, sc = p;
#pragma unroll
  for (int off = 1; off < 64; off <<= 1) {
    int t = __shfl_up(sc, off);
    if (lane >= off) sc += t;
  }
  if (lane == 63) wsum[wid] = sc;
  __syncthreads();
  if (tid < 8) {
    int ws = wsum[tid];
#pragma unroll
    for (int off = 1; off < 8; off <<= 1) {
      int t = __shfl_up(ws, off);
      if (tid >= off) ws += t;
    }
    wsum[tid] = ws;
  }
  __syncthreads();
  int excl = ((wid > 0) ? wsum[wid - 1] : 0) + sc - p;
  ncur[i0] = excl;
  ncur[i0 + 1] = excl + a0;
  int node0 = (b << BSHIFT) + i0;
  if (node0 < N_NODES) csr[node0] = ebase + excl;
  if (node0 + 1 < N_NODES) csr[node0 + 1] = ebase + excl + a0;
  if (b == 0 && tid == 0) csr[N_NODES] = N_EDGES;
  __syncthreads();
  for (int i = tid; i < myCnt; i += 512) {
    unsigned int pe = srcp[i];
    int pos = atomicAdd(&ncur[pe >> 17], 1);
    ssrc[ebase + pos] = (int)(pe & 0x1FFFF);
  }
}

// ---------------- aggregation (bf16 in/out, f32 accum) — skinny, high-occupancy ----------------

__global__ __launch_bounds__(256) void agg1_kernel(const unsigned int* __restrict__ x,
                                                   const int* __restrict__ csr,
                                                   const int* __restrict__ ssrc,
                                                   unsigned int* __restrict__ out) {
  int node = blockIdx.x * 4 + (threadIdx.x >> 6);
  int lane = threadIdx.x & 63;
  unsigned int u = x[(size_t)node * 64 + lane];
  float alo = bf_lo(u), ahi = bf_hi(u);
  int s = csr[node], e = csr[node + 1];
  int i = s;
  for (; i + 4 <= e; i += 4) {
    int n0 = ssrc[i], n1 = ssrc[i + 1], n2 = ssrc[i + 2], n3 = ssrc[i + 3];
    unsigned int v0 = x[(size_t)n0 * 64 + lane];
    unsigned int v1 = x[(size_t)n1 * 64 + lane];
    unsigned int v2 = x[(size_t)n2 * 64 + lane];
    unsigned int v3 = x[(size_t)n3 * 64 + lane];
    alo += bf_lo(v0) + bf_lo(v1) + bf_lo(v2) + bf_lo(v3);
    ahi += bf_hi(v0) + bf_hi(v1) + bf_hi(v2) + bf_hi(v3);
  }
  for (; i < e; i++) {
    unsigned int v = x[(size_t)ssrc[i] * 64 + lane];
    alo += bf_lo(v); ahi += bf_hi(v);
  }
  out[(size_t)node * 64 + lane] = packbf(alo, ahi);
}

__global__ __launch_bounds__(256) void agg2_kernel(const uint2* __restrict__ x,
                                                   const int* __restrict__ csr,
                                                   const int* __restrict__ ssrc,
                                                   uint2* __restrict__ out) {
  int node = blockIdx.x * 4 + (threadIdx.x >> 6);
  int lane = threadIdx.x & 63;
  uint2 u = x[(size_t)node * 64 + lane];
  float a0 = bf_lo(u.x), a1 = bf_hi(u.x), a2 = bf_lo(u.y), a3 = bf_hi(u.y);
  int s = csr[node], e = csr[node + 1];
  int i = s;
  for (; i + 4 <= e; i += 4) {
    int n0 = ssrc[i], n1 = ssrc[i + 1], n2 = ssrc[i + 2], n3 = ssrc[i + 3];
    uint2 v0 = x[(size_t)n0 * 64 + lane];
    uint2 v1 = x[(size_t)n1 * 64 + lane];
    uint2 v2 = x[(size_t)n2 * 64 + lane];
    uint2 v3 = x[(size_t)n3 * 64 + lane];
    a0 += bf_lo(v0.x) + bf_lo(v1.x) + bf_lo(v2.x) + bf_lo(v3.x);
    a1 += bf_hi(v0.x) + bf_hi(v1.x) + bf_hi(v2.x) + bf_hi(v3.x);
    a2 += bf_lo(v0.y) + bf_lo(v1.y) + bf_lo(v2.y) + bf_lo(v3.y);
    a3 += bf_hi(v0.y) + bf_hi(v1.y) + bf_hi(v2.y) + bf_hi(v3.y);
  }
  for (; i < e; i++) {
    uint2 v = x[(size_t)ssrc[i] * 64 + lane];
    a0 += bf_lo(v.x); a1 += bf_hi(v.x);
    a2 += bf_lo(v.y); a3 += bf_hi(v.y);
  }
  uint2 o;
  o.x = packbf(a0, a1);
  o.y = packbf(a2, a3);
  out[(size_t)node * 64 + lane] = o;
}

// ---------------- fused MLP v3: 128x256 tile, 8 waves, BK=64, full double-buffer ----------------
// A [N][K1] bf16; W1t [256][K1], W2t [256][256] bf16 (pre-transposed); C [N][256] bf16.
// LDS 128 KB: h1 [32][128][8] (64 KB; first 32 KB doubles as A-dbuf) + W dbuf 2x32 KB.
// 2-phase pipeline: STAGE(next) issued BEFORE MFMA(cur); one drain per K-step.
// W2 step0 prefetched during GEMM1's last step (no inter-GEMM bubble).
template<int K1, bool RELU2>
__global__ __launch_bounds__(512, 1)
void mlp_fused(const unsigned short* __restrict__ A,
               const unsigned short* __restrict__ W1t,
               const float* __restrict__ b1,
               const unsigned short* __restrict__ W2t,
               const float* __restrict__ b2,
               unsigned short* __restrict__ C) {
  __shared__ unsigned short Hsl[32 * 128 * 8];   // 64 KB: [ko2][m][8]
  __shared__ unsigned short Wsl[2][8 * 256 * 8]; // 2 x 32 KB: [ko][n][8]
  unsigned short* const Ab0 = Hsl;               // A dbuf overlays h1 region
  unsigned short* const Ab1 = Hsl + 8192;        // (dead once h1 is written)

  const int tid = threadIdx.x;
  const int lane = tid & 63;
  const int w = tid >> 6;          // 0..7
  const int wm = w >> 2;           // 0..1
  const int wn = w & 3;            // 0..3
  const int l15 = lane & 15, l4 = lane >> 4;
  const int rowBase = blockIdx.x * 128;
  constexpr int S1 = K1 / 64;

  auto stageW = [&](const unsigned short* Wt, int K, int k0, unsigned short* dst) {
#pragma unroll
    for (int i = 0; i < 4; i++) {
      int c = i * 512 + tid;                 // 0..2047
      int ko = c >> 8, n = c & 255;
      gload16(&Wt[(size_t)n * K + k0 + ko * 8], dst + (size_t)c * 8);
    }
  };
  auto stageA = [&](int k0, unsigned short* dst) {
#pragma unroll
    for (int i = 0; i < 2; i++) {
      int c = i * 512 + tid;                 // 0..1023
      int ko = c >> 7, m = c & 127;
      int gr = rowBase + m; if (gr >= N_NODES) gr = N_NODES - 1;
      gload16(&A[(size_t)gr * K1 + k0 + ko * 8], dst + (size_t)c * 8);
    }
  };

  // prologue
  stageA(0, Ab0);
  stageW(W1t, K1, 0, Wsl[0]);
  __syncthreads();

  f32x4 acc[4][4] = {};

  // ---- GEMM1 ----
  for (int s = 0; s < S1; s++) {
    if (s + 1 < S1) {
      stageA((s + 1) * 64, ((s + 1) & 1) ? Ab1 : Ab0);
      stageW(W1t, K1, (s + 1) * 64, Wsl[(s + 1) & 1]);
    } else {
      stageW(W2t, 256, 0, Wsl[(s + 1) & 1]);   // prefetch GEMM2 step 0
    }
    const unsigned short* Ac = (s & 1) ? Ab1 : Ab0;
    const unsigned short* Wc = Wsl[s & 1];
#pragma unroll
    for (int kk = 0; kk < 2; kk++) {
      int ko = kk * 4 + l4;
      bf16x8 a[4], b[4];
#pragma unroll
      for (int f = 0; f < 4; f++) {
        a[f] = *(const bf16x8*)&Ac[(size_t)(ko * 128 + wm * 64 + f * 16 + l15) * 8];
        b[f] = *(const bf16x8*)&Wc[(size_t)(ko * 256 + wn * 64 + f * 16 + l15) * 8];
      }
#pragma unroll
      for (int fm = 0; fm < 4; fm++)
#pragma unroll
        for (int fn = 0; fn < 4; fn++)
          acc[fm][fn] = __builtin_amdgcn_mfma_f32_16x16x32_bf16(a[fm], b[fn], acc[fm][fn], 0, 0, 0);
    }
    __syncthreads();
  }

  // ---- h1 -> LDS [ko2][m][8] (bias + relu), paired-dword writes ----
#pragma unroll
  for (int fm = 0; fm < 4; fm++) {
#pragma unroll
    for (int fn = 0; fn < 4; fn++) {
      int col = wn * 64 + fn * 16 + l15;
      float bb = b1[col];
#pragma unroll
      for (int j = 0; j < 4; j++) {
        int m = wm * 64 + fm * 16 + l4 * 4 + j;
        float v = fmaxf(acc[fm][fn][j] + bb, 0.f);
        float pv = __shfl_xor(v, 1);
        if ((l15 & 1) == 0) {
          int idx = (col >> 3) * 1024 + m * 8 + (col & 7);  // even -> dword aligned
          *(unsigned int*)&Hsl[idx] = packbf(v, pv);
        }
      }
      acc[fm][fn] = (f32x4){0.f, 0.f, 0.f, 0.f};
    }
  }
  __syncthreads();

  // ---- GEMM2 ----
  int wp = S1 & 1;
  for (int s2 = 0; s2 < 4; s2++) {
    if (s2 < 3) stageW(W2t, 256, (s2 + 1) * 64, Wsl[wp ^ 1]);
    const unsigned short* Wc = Wsl[wp];
#pragma unroll
    for (int kk = 0; kk < 2; kk++) {
      int ko = kk * 4 + l4;
      int ko2 = s2 * 8 + ko;
      bf16x8 a[4], b[4];
#pragma unroll
      for (int f = 0; f < 4; f++) {
        a[f] = *(const bf16x8*)&Hsl[(size_t)(ko2 * 128 + wm * 64 + f * 16 + l15) * 8];
        b[f] = *(const bf16x8*)&Wc[(size_t)(ko * 256 + wn * 64 + f * 16 + l15) * 8];
      }
#pragma unroll
      for (int fm = 0; fm < 4; fm++)
#pragma unroll
        for (int fn = 0; fn < 4; fn++)
          acc[fm][fn] = __builtin_amdgcn_mfma_f32_16x16x32_bf16(a[fm], b[fn], acc[fm][fn], 0, 0, 0);
    }
    __syncthreads();
    wp ^= 1;
  }

  // ---- epilogue ----
#pragma unroll
  for (int fm = 0; fm < 4; fm++) {
    int r0 = rowBase + wm * 64 + fm * 16 + l4 * 4;
#pragma unroll
    for (int fn = 0; fn < 4; fn++) {
      int col = wn * 64 + fn * 16 + l15;
      float bb = b2[col];
#pragma unroll
      for (int j = 0; j < 4; j++) {
        int r = r0 + j;
        if (r < N_NODES) {
          float v = acc[fm][fn][j] + bb;
          if (RELU2) v = fmaxf(v, 0.f);
          C[(size_t)r * HID + col] = f2bf(v);
        }
      }
    }
  }
}

// ---------------- pooling ----------------

__global__ __launch_bounds__(256) void pool_kernel(const unsigned short* __restrict__ H,
                                                   const int* __restrict__ batch,
                                                   float* __restrict__ sums,
                                                   float* __restrict__ cnts) {
  int d = threadIdx.x;
  int n0 = blockIdx.x * 128;
  int n1 = n0 + 128; if (n1 > N_NODES) n1 = N_NODES;
  int cur = batch[n0];
  float run = 0.f, runc = 0.f;
  for (int i = n0; i < n1; i++) {
    int b = batch[i];
    if (b != cur) {
      atomicAdd(&sums[(size_t)cur * HID + d], run);
      if (d == 0) atomicAdd(&cnts[cur], runc);
      run = 0.f; runc = 0.f; cur = b;
    }
    run += __uint_as_float(((unsigned int)H[(size_t)i * HID + d]) << 16);
    runc += 1.f;
  }
  atomicAdd(&sums[(size_t)cur * HID + d], run);
  if (d == 0) atomicAdd(&cnts[cur], runc);
}

// ---------------- head ----------------

__global__ __launch_bounds__(256) void head_kernel(const float* __restrict__ sums,
                                                   const float* __restrict__ cnts,
                                                   const float* __restrict__ gattr,
                                                   const float* __restrict__ wf1,
                                                   const float* __restrict__ bf1,
                                                   const float* __restrict__ wf2,
                                                   const float* __restrict__ bf2,
                                                   float* __restrict__ out) {
  int g = blockIdx.x, tid = threadIdx.x;
  __shared__ float gv[HID + GA];
  __shared__ float red[256];
  float c = cnts[g]; c = fmaxf(c, 1.0f);
  gv[tid] = sums[(size_t)g * HID + tid] / c;
  if (tid < GA) gv[HID + tid] = gattr[g * GA + tid];
  __syncthreads();
  float acc = bf1[tid];
  for (int k = 0; k < HID + GA; k++)
    acc = fmaf(gv[k], wf1[(size_t)k * HID + tid], acc);
  float h = fmaxf(acc, 0.f);
  red[tid] = h * wf2[tid];
  __syncthreads();
  for (int s = 128; s > 0; s >>= 1) {
    if (tid < s) red[tid] += red[tid + s];
    __syncthreads();
  }
  if (tid == 0) out[g] = red[0] + bf2[0];
}

// ---------------- launch ----------------

extern "C" void kernel_launch(void* const* d_in, const int* in_sizes, int n_in,
                              void* d_out, int out_size, void* d_ws, size_t ws_size,
                              hipStream_t stream) {
  const float* x     = (const float*)d_in[0];
  const int*   eidx  = (const int*)d_in[1];
  const int*   batch = (const int*)d_in[2];
  const float* gattr = (const float*)d_in[3];
  const float* w1a = (const float*)d_in[4];  const float* b1a = (const float*)d_in[5];
  const float* w1b = (const float*)d_in[6];  const float* b1b = (const float*)d_in[7];
  const float* w2a = (const float*)d_in[8];  const float* b2a = (const float*)d_in[9];
  const float* w2b = (const float*)d_in[10]; const float* b2b = (const float*)d_in[11];
  const float* wf1 = (const float*)d_in[12]; const float* bf1 = (const float*)d_in[13];
  const float* wf2 = (const float*)d_in[14]; const float* bf2 = (const float*)d_in[15];
  float* out = (float*)d_out;

  const int* esrc = eidx;
  const int* edst = eidx + N_EDGES;

  char* w = (char*)d_ws;
  auto alloc = [&](size_t bytes) -> void* {
    void* p = (void*)w;
    w += (bytes + 255) & ~(size_t)255;
    return p;
  };
  unsigned short* B0 = (unsigned short*)alloc((size_t)N_NODES * DIN * 2);  // x bf16
  unsigned short* B1 = (unsigned short*)alloc((size_t)N_NODES * HID * 2);
  unsigned short* B2 = (unsigned short*)alloc((size_t)N_NODES * HID * 2);
  unsigned short* w1aT = (unsigned short*)alloc(256 * 128 * 2);
  unsigned short* w1bT = (unsigned short*)alloc(256 * 256 * 2);
  unsigned short* w2aT = (unsigned short*)alloc(256 * 256 * 2);
  unsigned short* w2bT = (unsigned short*)alloc(256 * 256 * 2);
  int*   csr    = (int*)alloc((N_NODES + 4) * 4);
  int*   cursor = (int*)alloc(NBUCK * 4);
  unsigned int* tmp = (unsigned int*)alloc((size_t)NBUCK * BCAP * 4);
  int*   ssrc   = (int*)alloc((size_t)N_EDGES * 4);
  float* sums   = (float*)alloc((size_t)NGRAPH * HID * 4);
  float* cnts   = (float*)alloc(NGRAPH * 4);

  hipMemsetAsync(cursor, 0, NBUCK * 4, stream);
  hipMemsetAsync(sums, 0, (size_t)NGRAPH * HID * 4 + 256, stream);  // sums + cnts

  cvt_x_kernel<<<12500, 256, 0, stream>>>(x, B0);
  cvt_w_all<<<896, 256, 0, stream>>>(w1a, w1b, w2a, w2b, w1aT, w1bT, w2aT, w2bT);

  bin_kernel<<<(N_EDGES + 4095) / 4096, 256, 0, stream>>>(esrc, edst, cursor, tmp);
  sort_kernel<<<NBUCK, 512, 0, stream>>>(tmp, cursor, csr, ssrc);

  const int nconv = (N_NODES + 127) / 128;
  // conv1: agg (x bf16) -> B1[N][128]; MLP -> B2
  agg1_kernel<<<N_NODES / 4, 256, 0, stream>>>((const unsigned int*)B0, csr, ssrc,
                                               (unsigned int*)B1);
  mlp_fused<128, true><<<nconv, 512, 0, stream>>>(B1, w1aT, b1a, w1bT, b1b, B2);
  // conv2: agg (B2) -> B1[N][256]; MLP -> B2
  agg2_kernel<<<N_NODES / 4, 256, 0, stream>>>((const uint2*)B2, csr, ssrc, (uint2*)B1);
  mlp_fused<256, false><<<nconv, 512, 0, stream>>>(B1, w2aT, b2a, w2bT, b2b, B2);

  pool_kernel<<<(N_NODES + 127) / 128, 256, 0, stream>>>(B2, batch, sums, cnts);
  head_kernel<<<NGRAPH, 256, 0, stream>>>(sums, cnts, gattr, wf1, bf1, wf2, bf2, out);
}

// Round 7
// 478.173 us; speedup vs baseline: 1.4861x; 1.0670x over previous
//
#include <hip/hip_runtime.h>

#define N_NODES 100000
#define N_EDGES 1600000
#define NGRAPH  64
#define DIN     128
#define HID     256
#define GA      6

// bucketed CSR build
#define NBUCK  98        // ceil(100000 / 1024)
#define BSHIFT 10        // 1024 nodes per bucket
#define BCAP   20480     // per-bucket capacity (mean 16384, +32 sigma)

typedef __attribute__((ext_vector_type(8))) short bf16x8;
typedef __attribute__((ext_vector_type(4))) float f32x4;

__device__ __forceinline__ unsigned short f2bf(float f) {
  unsigned int u = __float_as_uint(f);
  u += 0x7fffu + ((u >> 16) & 1u);
  return (unsigned short)(u >> 16);
}
__device__ __forceinline__ float bf_lo(unsigned int u) { return __uint_as_float(u << 16); }
__device__ __forceinline__ float bf_hi(unsigned int u) { return __uint_as_float(u & 0xffff0000u); }
__device__ __forceinline__ unsigned int packbf(float lo, float hi) {
  return (unsigned int)f2bf(lo) | ((unsigned int)f2bf(hi) << 16);
}

__device__ __forceinline__ void gload16(const void* g, void* l) {
  __builtin_amdgcn_global_load_lds(
      (const __attribute__((address_space(1))) unsigned int*)g,
      (__attribute__((address_space(3))) unsigned int*)l, 16, 0, 0);
}

// ---------------- prep: f32 -> bf16 conversions ----------------

__global__ __launch_bounds__(256) void cvt_x_kernel(const float* __restrict__ in,
                                                    unsigned short* __restrict__ out) {
  size_t idx = ((size_t)blockIdx.x * 256 + threadIdx.x) * 4;  // 12.8M total, exact
  float4 v = *(const float4*)&in[idx];
  ushort4 o;
  o.x = f2bf(v.x); o.y = f2bf(v.y); o.z = f2bf(v.z); o.w = f2bf(v.w);
  *(ushort4*)&out[idx] = o;
}

// all four weight transposes in one launch: out[n*K+k] = bf16(in[k*256+n])
__global__ __launch_bounds__(256) void cvt_w_all(const float* __restrict__ w1a,
                                                 const float* __restrict__ w1b,
                                                 const float* __restrict__ w2a,
                                                 const float* __restrict__ w2b,
                                                 unsigned short* __restrict__ o1a,
                                                 unsigned short* __restrict__ o1b,
                                                 unsigned short* __restrict__ o2a,
                                                 unsigned short* __restrict__ o2b) {
  int bid = blockIdx.x, tid = threadIdx.x;
  const float* in; unsigned short* out; int shift, idx;
  if (bid < 128)      { in = w1a; out = o1a; shift = 7; idx = bid * 256 + tid; }
  else if (bid < 384) { in = w1b; out = o1b; shift = 8; idx = (bid - 128) * 256 + tid; }
  else if (bid < 640) { in = w2a; out = o2a; shift = 8; idx = (bid - 384) * 256 + tid; }
  else                { in = w2b; out = o2b; shift = 8; idx = (bid - 640) * 256 + tid; }
  int K = 1 << shift;
  int n = idx >> shift;
  int k = idx & (K - 1);
  out[idx] = f2bf(in[(size_t)k * HID + n]);
}

// ---------------- pass 1: bin edges by dst>>10 with block-local sort ----------------

__global__ __launch_bounds__(256) void bin_kernel(const int* __restrict__ esrc,
                                                  const int* __restrict__ edst,
                                                  int* __restrict__ cursor,
                                                  unsigned int* __restrict__ tmp) {
  __shared__ unsigned int pk[4096];
  __shared__ int hist[NBUCK], lbase[NBUCK + 1], gbase[NBUCK], lcur[NBUCK];
  const int tid = threadIdx.x;
  const int lane = tid & 63;
  const int ebase = blockIdx.x * 4096;
  const int n = min(4096, N_EDGES - ebase);
  if (tid < NBUCK) hist[tid] = 0;
  __syncthreads();
  unsigned int pkv[16]; int bk[16];
#pragma unroll
  for (int i = 0; i < 16; i++) {
    int e = ebase + i * 256 + tid;
    bk[i] = -1;
    if (e < N_EDGES) {
      int s = esrc[e], d = edst[e];
      bk[i] = d >> BSHIFT;
      pkv[i] = (unsigned int)s | ((unsigned int)(d & ((1 << BSHIFT) - 1)) << 17);
      atomicAdd(&hist[bk[i]], 1);
    }
  }
  __syncthreads();
  if (tid < 64) {
    int i0 = 2 * tid, i1 = i0 + 1;
    int a0 = (i0 < NBUCK) ? hist[i0] : 0;
    int a1 = (i1 < NBUCK) ? hist[i1] : 0;
    int p = a0 + a1, sc = p;
#pragma unroll
    for (int off = 1; off < 64; off <<= 1) {
      int t = __shfl_up(sc, off);
      if (lane >= off) sc += t;
    }
    int excl = sc - p;
    if (i0 < NBUCK) lbase[i0] = excl;
    if (i1 < NBUCK) lbase[i1] = excl + a0;
    if (tid == 63) lbase[NBUCK] = sc;
  }
  __syncthreads();
  if (tid < NBUCK) {
    int c = hist[tid];
    gbase[tid] = c ? atomicAdd(&cursor[tid], c) : 0;
    lcur[tid] = lbase[tid];
  }
  __syncthreads();
#pragma unroll
  for (int i = 0; i < 16; i++) {
    if (bk[i] >= 0) {
      int pos = atomicAdd(&lcur[bk[i]], 1);
      pk[pos] = pkv[i];
    }
  }
  __syncthreads();
#pragma unroll
  for (int i = 0; i < 16; i++) {
    int idx = i * 256 + tid;
    if (idx < n) {
      int lo = 0, hi = NBUCK;
      while (hi - lo > 1) {
        int mid = (lo + hi) >> 1;
        if (lbase[mid] <= idx) lo = mid; else hi = mid;
      }
      tmp[(size_t)lo * BCAP + gbase[lo] + (idx - lbase[lo])] = pk[idx];
    }
  }
}

// ---------------- pass 2: per-bucket counting sort -> csr + ssrc ----------------

__global__ __launch_bounds__(512) void sort_kernel(const unsigned int* __restrict__ tmp,
                                                   const int* __restrict__ cnt,
                                                   int* __restrict__ csr,
                                                   int* __restrict__ ssrc) {
  __shared__ int nhist[1024], ncur[1024];
  __shared__ int bb[NBUCK];
  __shared__ int wsum[8];
  const int b = blockIdx.x;
  const int tid = threadIdx.x;
  const int lane = tid & 63, wid = tid >> 6;
  if (tid < 64) {
    int i0 = 2 * tid, i1 = i0 + 1;
    int a0 = (i0 < NBUCK) ? cnt[i0] : 0;
    int a1 = (i1 < NBUCK) ? cnt[i1] : 0;
    int p = a0 + a1, sc = p;
#pragma unroll
    for (int off = 1; off < 64; off <<= 1) {
      int t = __shfl_up(sc, off);
      if (lane >= off) sc += t;
    }
    int excl = sc - p;
    if (i0 < NBUCK) bb[i0] = excl;
    if (i1 < NBUCK) bb[i1] = excl + a0;
  }
  nhist[tid] = 0; nhist[tid + 512] = 0;
  __syncthreads();
  const int myCnt = cnt[b];
  const int ebase = bb[b];
  const unsigned int* srcp = tmp + (size_t)b * BCAP;
  for (int i = tid; i < myCnt; i += 512)
    atomicAdd(&nhist[srcp[i] >> 17], 1);
  __syncthreads();
  int i0 = 2 * tid;
  int a0 = nhist[i0], a1 = nhist[i0 + 1];
  int p = a0 + a1, sc = p;
#pragma unroll
  for (int off = 1; off < 64; off <<= 1) {
    int t = __shfl_up(sc, off);
    if (lane >= off) sc += t;
  }
  if (lane == 63) wsum[wid] = sc;
  __syncthreads();
  if (tid < 8) {
    int ws = wsum[tid];
#pragma unroll
    for (int off = 1; off < 8; off <<= 1) {
      int t = __shfl_up(ws, off);
      if (tid >= off) ws += t;
    }
    wsum[tid] = ws;
  }
  __syncthreads();
  int excl = ((wid > 0) ? wsum[wid - 1] : 0) + sc - p;
  ncur[i0] = excl;
  ncur[i0 + 1] = excl + a0;
  int node0 = (b << BSHIFT) + i0;
  if (node0 < N_NODES) csr[node0] = ebase + excl;
  if (node0 + 1 < N_NODES) csr[node0 + 1] = ebase + excl + a0;
  if (b == 0 && tid == 0) csr[N_NODES] = N_EDGES;
  __syncthreads();
  for (int i = tid; i < myCnt; i += 512) {
    unsigned int pe = srcp[i];
    int pos = atomicAdd(&ncur[pe >> 17], 1);
    ssrc[ebase + pos] = (int)(pe & 0x1FFFF);
  }
}

// ---------------- aggregation (bf16 in/out, f32 accum) — skinny, high-occupancy ----------------

__global__ __launch_bounds__(256) void agg1_kernel(const unsigned int* __restrict__ x,
                                                   const int* __restrict__ csr,
                                                   const int* __restrict__ ssrc,
                                                   unsigned int* __restrict__ out) {
  int node = blockIdx.x * 4 + (threadIdx.x >> 6);
  int lane = threadIdx.x & 63;
  unsigned int u = x[(size_t)node * 64 + lane];
  float alo = bf_lo(u), ahi = bf_hi(u);
  int s = csr[node], e = csr[node + 1];
  int i = s;
  for (; i + 4 <= e; i += 4) {
    int n0 = ssrc[i], n1 = ssrc[i + 1], n2 = ssrc[i + 2], n3 = ssrc[i + 3];
    unsigned int v0 = x[(size_t)n0 * 64 + lane];
    unsigned int v1 = x[(size_t)n1 * 64 + lane];
    unsigned int v2 = x[(size_t)n2 * 64 + lane];
    unsigned int v3 = x[(size_t)n3 * 64 + lane];
    alo += bf_lo(v0) + bf_lo(v1) + bf_lo(v2) + bf_lo(v3);
    ahi += bf_hi(v0) + bf_hi(v1) + bf_hi(v2) + bf_hi(v3);
  }
  for (; i < e; i++) {
    unsigned int v = x[(size_t)ssrc[i] * 64 + lane];
    alo += bf_lo(v); ahi += bf_hi(v);
  }
  out[(size_t)node * 64 + lane] = packbf(alo, ahi);
}

__global__ __launch_bounds__(256) void agg2_kernel(const uint2* __restrict__ x,
                                                   const int* __restrict__ csr,
                                                   const int* __restrict__ ssrc,
                                                   uint2* __restrict__ out) {
  int node = blockIdx.x * 4 + (threadIdx.x >> 6);
  int lane = threadIdx.x & 63;
  uint2 u = x[(size_t)node * 64 + lane];
  float a0 = bf_lo(u.x), a1 = bf_hi(u.x), a2 = bf_lo(u.y), a3 = bf_hi(u.y);
  int s = csr[node], e = csr[node + 1];
  int i = s;
  for (; i + 4 <= e; i += 4) {
    int n0 = ssrc[i], n1 = ssrc[i + 1], n2 = ssrc[i + 2], n3 = ssrc[i + 3];
    uint2 v0 = x[(size_t)n0 * 64 + lane];
    uint2 v1 = x[(size_t)n1 * 64 + lane];
    uint2 v2 = x[(size_t)n2 * 64 + lane];
    uint2 v3 = x[(size_t)n3 * 64 + lane];
    a0 += bf_lo(v0.x) + bf_lo(v1.x) + bf_lo(v2.x) + bf_lo(v3.x);
    a1 += bf_hi(v0.x) + bf_hi(v1.x) + bf_hi(v2.x) + bf_hi(v3.x);
    a2 += bf_lo(v0.y) + bf_lo(v1.y) + bf_lo(v2.y) + bf_lo(v3.y);
    a3 += bf_hi(v0.y) + bf_hi(v1.y) + bf_hi(v2.y) + bf_hi(v3.y);
  }
  for (; i < e; i++) {
    uint2 v = x[(size_t)ssrc[i] * 64 + lane];
    a0 += bf_lo(v.x); a1 += bf_hi(v.x);
    a2 += bf_lo(v.y); a3 += bf_hi(v.y);
  }
  uint2 o;
  o.x = packbf(a0, a1);
  o.y = packbf(a2, a3);
  out[(size_t)node * 64 + lane] = o;
}

// ---------------- fused MLP v4: coalesced swizzled staging ----------------
// Layouts (bf16 elems):
//   A tile  [128][64] row-major, chunk-XOR: elem(m,k)  = m*64  + ((k>>3)^(m&7))*8 + (k&7)
//   W tile  [256][64] row-major, chunk-XOR: elem(n,k)  = n*64  + ((k>>3)^(n&7))*8 + (k&7)
//   h1      [128][256] row-major, chunk-XOR: elem(m,k) = m*256 + ((k>>3)^(m&7))*8 + (k&7)
// Staging: chunk c -> row=c>>3, koL=c&7, SOURCE k-chunk = koL^(row&7); LDS dest linear
// (c*16 bytes). 8 lanes of a row read a permuted contiguous 128 B -> coalesced.
// All ds_read_b128 / dword writes land 2-way max on banks (free).
template<int K1, bool RELU2>
__global__ __launch_bounds__(512, 1)
void mlp_fused(const unsigned short* __restrict__ A,
               const unsigned short* __restrict__ W1t,
               const float* __restrict__ b1,
               const unsigned short* __restrict__ W2t,
               const float* __restrict__ b2,
               unsigned short* __restrict__ C) {
  __shared__ unsigned short Hsl[128 * 256];      // 64 KB
  __shared__ unsigned short Wsl[2][256 * 64];    // 2 x 32 KB
  unsigned short* const Ab0 = Hsl;               // A dbuf overlays h1 region
  unsigned short* const Ab1 = Hsl + 128 * 64;    // (dead once h1 is written)

  const int tid = threadIdx.x;
  const int lane = tid & 63;
  const int w = tid >> 6;          // 0..7
  const int wm = w >> 2;           // 0..1
  const int wn = w & 3;            // 0..3
  const int l15 = lane & 15, l4 = lane >> 4;
  const int l7 = l15 & 7;          // XOR operand for fragment reads
  const int rowBase = blockIdx.x * 128;
  constexpr int S1 = K1 / 64;

  auto stageW = [&](const unsigned short* Wt, int K, int k0, unsigned short* dst) {
#pragma unroll
    for (int i = 0; i < 4; i++) {
      int c = i * 512 + tid;                 // 0..2047
      int n = c >> 3, koL = c & 7;
      int koS = koL ^ (n & 7);
      gload16(&Wt[(size_t)n * K + k0 + koS * 8], dst + (size_t)c * 8);
    }
  };
  auto stageA = [&](int k0, unsigned short* dst) {
#pragma unroll
    for (int i = 0; i < 2; i++) {
      int c = i * 512 + tid;                 // 0..1023
      int m = c >> 3, koL = c & 7;
      int koS = koL ^ (m & 7);
      int gr = rowBase + m; if (gr >= N_NODES) gr = N_NODES - 1;
      gload16(&A[(size_t)gr * K1 + k0 + koS * 8], dst + (size_t)c * 8);
    }
  };

  // prologue
  stageA(0, Ab0);
  stageW(W1t, K1, 0, Wsl[0]);
  __syncthreads();

  f32x4 acc[4][4] = {};

  // ---- GEMM1 ----
  for (int s = 0; s < S1; s++) {
    if (s + 1 < S1) {
      stageA((s + 1) * 64, ((s + 1) & 1) ? Ab1 : Ab0);
      stageW(W1t, K1, (s + 1) * 64, Wsl[(s + 1) & 1]);
    } else {
      stageW(W2t, 256, 0, Wsl[(s + 1) & 1]);   // prefetch GEMM2 step 0
    }
    const unsigned short* Ac = (s & 1) ? Ab1 : Ab0;
    const unsigned short* Wc = Wsl[s & 1];
#pragma unroll
    for (int kk = 0; kk < 2; kk++) {
      int koX = (kk * 4 + l4) ^ l7;        // pre-XORed chunk index
      bf16x8 a[4], b[4];
#pragma unroll
      for (int f = 0; f < 4; f++) {
        int rowA = wm * 64 + f * 16 + l15;
        int rowB = wn * 64 + f * 16 + l15;
        a[f] = *(const bf16x8*)&Ac[(size_t)(rowA * 64 + koX * 8)];
        b[f] = *(const bf16x8*)&Wc[(size_t)(rowB * 64 + koX * 8)];
      }
#pragma unroll
      for (int fm = 0; fm < 4; fm++)
#pragma unroll
        for (int fn = 0; fn < 4; fn++)
          acc[fm][fn] = __builtin_amdgcn_mfma_f32_16x16x32_bf16(a[fm], b[fn], acc[fm][fn], 0, 0, 0);
    }
    __syncthreads();
  }

  // ---- h1 -> LDS (bias + relu), paired-dword swizzled writes ----
#pragma unroll
  for (int fm = 0; fm < 4; fm++) {
#pragma unroll
    for (int fn = 0; fn < 4; fn++) {
      int col = wn * 64 + fn * 16 + l15;
      float bb = b1[col];
#pragma unroll
      for (int j = 0; j < 4; j++) {
        int m = wm * 64 + fm * 16 + l4 * 4 + j;
        float v = fmaxf(acc[fm][fn][j] + bb, 0.f);
        float pv = __shfl_xor(v, 1);
        if ((l15 & 1) == 0) {
          int idx = m * 256 + (((col >> 3) ^ (m & 7)) << 3) + (col & 7);  // even
          *(unsigned int*)&Hsl[idx] = packbf(v, pv);
        }
      }
      acc[fm][fn] = (f32x4){0.f, 0.f, 0.f, 0.f};
    }
  }
  __syncthreads();

  // ---- GEMM2 ----
  int wp = S1 & 1;
  for (int s2 = 0; s2 < 4; s2++) {
    if (s2 < 3) stageW(W2t, 256, (s2 + 1) * 64, Wsl[wp ^ 1]);
    const unsigned short* Wc = Wsl[wp];
#pragma unroll
    for (int kk = 0; kk < 2; kk++) {
      int ko = kk * 4 + l4;                // 0..7 within W tile
      int koXw = ko ^ l7;
      int koXh = (s2 * 8 + ko) ^ l7;       // 0..31 within h1
      bf16x8 a[4], b[4];
#pragma unroll
      for (int f = 0; f < 4; f++) {
        int rowA = wm * 64 + f * 16 + l15;
        int rowB = wn * 64 + f * 16 + l15;
        a[f] = *(const bf16x8*)&Hsl[(size_t)(rowA * 256 + koXh * 8)];
        b[f] = *(const bf16x8*)&Wc[(size_t)(rowB * 64 + koXw * 8)];
      }
#pragma unroll
      for (int fm = 0; fm < 4; fm++)
#pragma unroll
        for (int fn = 0; fn < 4; fn++)
          acc[fm][fn] = __builtin_amdgcn_mfma_f32_16x16x32_bf16(a[fm], b[fn], acc[fm][fn], 0, 0, 0);
    }
    __syncthreads();
    wp ^= 1;
  }

  // ---- epilogue ----
#pragma unroll
  for (int fm = 0; fm < 4; fm++) {
    int r0 = rowBase + wm * 64 + fm * 16 + l4 * 4;
#pragma unroll
    for (int fn = 0; fn < 4; fn++) {
      int col = wn * 64 + fn * 16 + l15;
      float bb = b2[col];
#pragma unroll
      for (int j = 0; j < 4; j++) {
        int r = r0 + j;
        if (r < N_NODES) {
          float v = acc[fm][fn][j] + bb;
          if (RELU2) v = fmaxf(v, 0.f);
          C[(size_t)r * HID + col] = f2bf(v);
        }
      }
    }
  }
}

// ---------------- pooling ----------------

__global__ __launch_bounds__(256) void pool_kernel(const unsigned short* __restrict__ H,
                                                   const int* __restrict__ batch,
                                                   float* __restrict__ sums,
                                                   float* __restrict__ cnts) {
  int d = threadIdx.x;
  int n0 = blockIdx.x * 128;
  int n1 = n0 + 128; if (n1 > N_NODES) n1 = N_NODES;
  int cur = batch[n0];
  float run = 0.f, runc = 0.f;
  for (int i = n0; i < n1; i++) {
    int b = batch[i];
    if (b != cur) {
      atomicAdd(&sums[(size_t)cur * HID + d], run);
      if (d == 0) atomicAdd(&cnts[cur], runc);
      run = 0.f; runc = 0.f; cur = b;
    }
    run += __uint_as_float(((unsigned int)H[(size_t)i * HID + d]) << 16);
    runc += 1.f;
  }
  atomicAdd(&sums[(size_t)cur * HID + d], run);
  if (d == 0) atomicAdd(&cnts[cur], runc);
}

// ---------------- head ----------------

__global__ __launch_bounds__(256) void head_kernel(const float* __restrict__ sums,
                                                   const float* __restrict__ cnts,
                                                   const float* __restrict__ gattr,
                                                   const float* __restrict__ wf1,
                                                   const float* __restrict__ bf1,
                                                   const float* __restrict__ wf2,
                                                   const float* __restrict__ bf2,
                                                   float* __restrict__ out) {
  int g = blockIdx.x, tid = threadIdx.x;
  __shared__ float gv[HID + GA];
  __shared__ float red[256];
  float c = cnts[g]; c = fmaxf(c, 1.0f);
  gv[tid] = sums[(size_t)g * HID + tid] / c;
  if (tid < GA) gv[HID + tid] = gattr[g * GA + tid];
  __syncthreads();
  float acc = bf1[tid];
  for (int k = 0; k < HID + GA; k++)
    acc = fmaf(gv[k], wf1[(size_t)k * HID + tid], acc);
  float h = fmaxf(acc, 0.f);
  red[tid] = h * wf2[tid];
  __syncthreads();
  for (int s = 128; s > 0; s >>= 1) {
    if (tid < s) red[tid] += red[tid + s];
    __syncthreads();
  }
  if (tid == 0) out[g] = red[0] + bf2[0];
}

// ---------------- launch ----------------

extern "C" void kernel_launch(void* const* d_in, const int* in_sizes, int n_in,
                              void* d_out, int out_size, void* d_ws, size_t ws_size,
                              hipStream_t stream) {
  const float* x     = (const float*)d_in[0];
  const int*   eidx  = (const int*)d_in[1];
  const int*   batch = (const int*)d_in[2];
  const float* gattr = (const float*)d_in[3];
  const float* w1a = (const float*)d_in[4];  const float* b1a = (const float*)d_in[5];
  const float* w1b = (const float*)d_in[6];  const float* b1b = (const float*)d_in[7];
  const float* w2a = (const float*)d_in[8];  const float* b2a = (const float*)d_in[9];
  const float* w2b = (const float*)d_in[10]; const float* b2b = (const float*)d_in[11];
  const float* wf1 = (const float*)d_in[12]; const float* bf1 = (const float*)d_in[13];
  const float* wf2 = (const float*)d_in[14]; const float* bf2 = (const float*)d_in[15];
  float* out = (float*)d_out;

  const int* esrc = eidx;
  const int* edst = eidx + N_EDGES;

  char* w = (char*)d_ws;
  auto alloc = [&](size_t bytes) -> void* {
    void* p = (void*)w;
    w += (bytes + 255) & ~(size_t)255;
    return p;
  };
  unsigned short* B0 = (unsigned short*)alloc((size_t)N_NODES * DIN * 2);  // x bf16
  unsigned short* B1 = (unsigned short*)alloc((size_t)N_NODES * HID * 2);
  unsigned short* B2 = (unsigned short*)alloc((size_t)N_NODES * HID * 2);
  unsigned short* w1aT = (unsigned short*)alloc(256 * 128 * 2);
  unsigned short* w1bT = (unsigned short*)alloc(256 * 256 * 2);
  unsigned short* w2aT = (unsigned short*)alloc(256 * 256 * 2);
  unsigned short* w2bT = (unsigned short*)alloc(256 * 256 * 2);
  int*   csr    = (int*)alloc((N_NODES + 4) * 4);
  int*   cursor = (int*)alloc(NBUCK * 4);
  unsigned int* tmp = (unsigned int*)alloc((size_t)NBUCK * BCAP * 4);
  int*   ssrc   = (int*)alloc((size_t)N_EDGES * 4);
  float* sums   = (float*)alloc((size_t)NGRAPH * HID * 4);
  float* cnts   = (float*)alloc(NGRAPH * 4);

  hipMemsetAsync(cursor, 0, NBUCK * 4, stream);
  hipMemsetAsync(sums, 0, (size_t)NGRAPH * HID * 4 + 256, stream);  // sums + cnts

  cvt_x_kernel<<<12500, 256, 0, stream>>>(x, B0);
  cvt_w_all<<<896, 256, 0, stream>>>(w1a, w1b, w2a, w2b, w1aT, w1bT, w2aT, w2bT);

  bin_kernel<<<(N_EDGES + 4095) / 4096, 256, 0, stream>>>(esrc, edst, cursor, tmp);
  sort_kernel<<<NBUCK, 512, 0, stream>>>(tmp, cursor, csr, ssrc);

  const int nconv = (N_NODES + 127) / 128;
  // conv1: agg (x bf16) -> B1[N][128]; MLP -> B2
  agg1_kernel<<<N_NODES / 4, 256, 0, stream>>>((const unsigned int*)B0, csr, ssrc,
                                               (unsigned int*)B1);
  mlp_fused<128, true><<<nconv, 512, 0, stream>>>(B1, w1aT, b1a, w1bT, b1b, B2);
  // conv2: agg (B2) -> B1[N][256]; MLP -> B2
  agg2_kernel<<<N_NODES / 4, 256, 0, stream>>>((const uint2*)B2, csr, ssrc, (uint2*)B1);
  mlp_fused<256, false><<<nconv, 512, 0, stream>>>(B1, w2aT, b2a, w2bT, b2b, B2);

  pool_kernel<<<(N_NODES + 127) / 128, 256, 0, stream>>>(B2, batch, sums, cnts);
  head_kernel<<<NGRAPH, 256, 0, stream>>>(sums, cnts, gattr, wf1, bf1, wf2, bf2, out);
}